// Round 10
// baseline (398.921 us; speedup 1.0000x reference)
//
#include <hip/hip_runtime.h>

// Problem constants (fixed by the reference setup)
constexpr int NN = 100000;   // nodes
constexpr int RR = 8;        // relations
constexpr int BB = 4;        // bases
constexpr int DD = 64;       // feature dim
constexpr int EE = 2000000;  // edges
constexpr int PP = 500000;   // pairs
constexpr int CAP = 64;      // fixed per-node bucket capacity (deg ~ Poisson(20))

constexpr int NBINS = 8;             // one per XCD
constexpr int BIN_NODES = NN / NBINS;  // 12500
constexpr int BINCAP = 262144;       // per-bin record capacity (expect ~250k, 25 sigma slack)
constexpr int EPB = 2048;            // edges per bin_kernel block

typedef __attribute__((ext_vector_type(8))) short short8;      // 8 bf16 MFMA frag
typedef __attribute__((ext_vector_type(4))) unsigned short ushort4v;
typedef __attribute__((ext_vector_type(4))) float f32x4;

// ---------------------------------------------------------------------------
// bf16 helpers (RNE)
__device__ __forceinline__ unsigned short f2bf(float f) {
    unsigned u = __float_as_uint(f);
    u += 0x7FFFu + ((u >> 16) & 1u);
    return (unsigned short)(u >> 16);
}
__device__ __forceinline__ float bf2f(unsigned short b) {
    return __uint_as_float(((unsigned)b) << 16);
}

// f32 -> bf16 plane copy (vectorized)
__global__ void tobf16_kernel(const float* __restrict__ in, unsigned short* __restrict__ out,
                              int n4) {
    int i = blockIdx.x * blockDim.x + threadIdx.x;
    if (i >= n4) return;
    float4 v = reinterpret_cast<const float4*>(in)[i];
    ushort4v o;
    o.x = f2bf(v.x); o.y = f2bf(v.y); o.z = f2bf(v.z); o.w = f2bf(v.w);
    reinterpret_cast<ushort4v*>(out)[i] = o;
}

// ---------------------------------------------------------------------------
// Phase 1: partition edges into NBINS bins by dst node range.
// Per-block LDS histogram -> one global atomic per bin -> append (payload,dst).
__global__ void bin_kernel(const int* __restrict__ src, const int* __restrict__ dst,
                           const int* __restrict__ et, int* __restrict__ bin_cursor,
                           uint2* __restrict__ ebin) {
    __shared__ int lcount[NBINS];
    __shared__ int lbase[NBINS];
    int tid = threadIdx.x;
    if (tid < NBINS) lcount[tid] = 0;
    __syncthreads();

    int e0 = blockIdx.x * EPB;
    int mybin[8];
    int myrank[8];
    uint2 myrec[8];
#pragma unroll
    for (int j = 0; j < 8; ++j) {
        int e = e0 + j * 256 + tid;
        bool valid = e < EE;
        int d = valid ? dst[e] : 0;
        int b = d / BIN_NODES;
        mybin[j] = b;
        if (valid) {
            myrec[j].x = (unsigned)src[e] | ((unsigned)et[e] << 24);
            myrec[j].y = (unsigned)d;
            myrank[j] = atomicAdd(&lcount[b], 1);
        } else {
            myrank[j] = -1;
        }
    }
    __syncthreads();
    if (tid < NBINS) lbase[tid] = atomicAdd(&bin_cursor[tid], lcount[tid]);
    __syncthreads();
#pragma unroll
    for (int j = 0; j < 8; ++j) {
        if (myrank[j] >= 0) {
            int pos = lbase[mybin[j]] + myrank[j];
            ebin[(size_t)mybin[j] * BINCAP + pos] = myrec[j];
        }
    }
}

// Phase 2: per-bin scatter into fixed 64-slot node buckets. Blocks sharing a
// bin share blockIdx%8 -> co-locate on one XCD (heuristic); the bin's epack
// slice (3.2 MB) + cnt slice (50 KB) then stay L2-resident.
__global__ void scatter2_kernel(const uint2* __restrict__ ebin,
                                const int* __restrict__ bin_cursor,
                                int* __restrict__ cnt, unsigned* __restrict__ epack) {
    int bin = blockIdx.x & (NBINS - 1);
    int chunk = blockIdx.x / NBINS;
    int nchunks = gridDim.x / NBINS;
    int m = bin_cursor[bin];
    const uint2* base = ebin + (size_t)bin * BINCAP;
    for (int i = chunk * 256 + threadIdx.x; i < m; i += nchunks * 256) {
        uint2 rec = base[i];
        int d = (int)rec.y;
        int r = atomicAdd(&cnt[d], 1);
        if (r < CAP) epack[(size_t)d * CAP + r] = rec.x;
    }
}

// ---------------------------------------------------------------------------
// Basis-space aggregation over bf16 features, fixed-bucket CSR (deg <= 64 ->
// exactly one 64-edge window). Per-relation mean denominators recovered
// in-wave via ballot/popcount over the loaded edge packs.
// Half-wave h (lane>>5) processes edges k+h; lane covers features 2*(lane&31)+{0,1}.
__global__ void aggregate_kernel(const unsigned short* __restrict__ x,
                                 const unsigned* __restrict__ epack,
                                 const int* __restrict__ cnt,
                                 const float* __restrict__ comp,
                                 unsigned short* __restrict__ y) {
    __shared__ float wlds[4 * 32];  // [wave][r*4+b]
    int lane = threadIdx.x & 63;
    int wid = threadIdx.x >> 6;
    int n = blockIdx.x * 4 + wid;
    int half = lane >> 5;
    int fl = lane & 31;

    int m = cnt[n];
    if (m > CAP) m = CAP;

    unsigned pl = (lane < m) ? epack[(size_t)n * CAP + lane] : 0u;
    int et_l = (int)(pl >> 24);

    // per-relation counts via 8 wave-wide ballots (register-only, uniform)
    int cr0 = __popcll(__ballot((lane < m) && (et_l == 0)));
    int cr1 = __popcll(__ballot((lane < m) && (et_l == 1)));
    int cr2 = __popcll(__ballot((lane < m) && (et_l == 2)));
    int cr3 = __popcll(__ballot((lane < m) && (et_l == 3)));
    int cr4 = __popcll(__ballot((lane < m) && (et_l == 4)));
    int cr5 = __popcll(__ballot((lane < m) && (et_l == 5)));
    int cr6 = __popcll(__ballot((lane < m) && (et_l == 6)));
    int cr7 = __popcll(__ballot((lane < m) && (et_l == 7)));

    if (lane < 32) {
        int r = lane >> 2;
        int myc = cr0;
        myc = (r == 1) ? cr1 : myc;
        myc = (r == 2) ? cr2 : myc;
        myc = (r == 3) ? cr3 : myc;
        myc = (r == 4) ? cr4 : myc;
        myc = (r == 5) ? cr5 : myc;
        myc = (r == 6) ? cr6 : myc;
        myc = (r == 7) ? cr7 : myc;
        wlds[wid * 32 + lane] = comp[lane] / fmaxf((float)myc, 1.f);
    }
    __syncthreads();

    float a0x = 0.f, a0y = 0.f, a1x = 0.f, a1y = 0.f;
    float a2x = 0.f, a2y = 0.f, a3x = 0.f, a3y = 0.f;

    int k = 0;
    for (; k + 4 <= m; k += 4) {  // 4 edges per iteration (2 per half-wave)
        unsigned pA = __shfl(pl, k + half);
        unsigned pB = __shfl(pl, k + 2 + half);
        unsigned rA = *reinterpret_cast<const unsigned*>(
            x + (size_t)(pA & 0xFFFFFFu) * 64 + fl * 2);
        unsigned rB = *reinterpret_cast<const unsigned*>(
            x + (size_t)(pB & 0xFFFFFFu) * 64 + fl * 2);
        float4 wA = *reinterpret_cast<const float4*>(&wlds[wid * 32 + (pA >> 24) * 4]);
        float4 wB = *reinterpret_cast<const float4*>(&wlds[wid * 32 + (pB >> 24) * 4]);
        float rAx = bf2f((unsigned short)(rA & 0xFFFF));
        float rAy = bf2f((unsigned short)(rA >> 16));
        float rBx = bf2f((unsigned short)(rB & 0xFFFF));
        float rBy = bf2f((unsigned short)(rB >> 16));
        a0x = fmaf(wA.x, rAx, a0x); a0y = fmaf(wA.x, rAy, a0y);
        a1x = fmaf(wA.y, rAx, a1x); a1y = fmaf(wA.y, rAy, a1y);
        a2x = fmaf(wA.z, rAx, a2x); a2y = fmaf(wA.z, rAy, a2y);
        a3x = fmaf(wA.w, rAx, a3x); a3y = fmaf(wA.w, rAy, a3y);
        a0x = fmaf(wB.x, rBx, a0x); a0y = fmaf(wB.x, rBy, a0y);
        a1x = fmaf(wB.y, rBx, a1x); a1y = fmaf(wB.y, rBy, a1y);
        a2x = fmaf(wB.z, rBx, a2x); a2y = fmaf(wB.z, rBy, a2y);
        a3x = fmaf(wB.w, rBx, a3x); a3y = fmaf(wB.w, rBy, a3y);
    }
    for (; k < m; k += 2) {  // 0..3 remaining edges
        int ki = k + half;
        int kc = (ki < m) ? ki : k;
        float sc = (ki < m) ? 1.f : 0.f;
        unsigned p = __shfl(pl, kc);
        unsigned rv = *reinterpret_cast<const unsigned*>(
            x + (size_t)(p & 0xFFFFFFu) * 64 + fl * 2);
        float4 wv = *reinterpret_cast<const float4*>(&wlds[wid * 32 + (p >> 24) * 4]);
        float rx = bf2f((unsigned short)(rv & 0xFFFF)) * sc;
        float ry = bf2f((unsigned short)(rv >> 16)) * sc;
        a0x = fmaf(wv.x, rx, a0x); a0y = fmaf(wv.x, ry, a0y);
        a1x = fmaf(wv.y, rx, a1x); a1y = fmaf(wv.y, ry, a1y);
        a2x = fmaf(wv.z, rx, a2x); a2y = fmaf(wv.z, ry, a2y);
        a3x = fmaf(wv.w, rx, a3x); a3y = fmaf(wv.w, ry, a3y);
    }

    // merge the two half-wave partial sums
    a0x += __shfl_xor(a0x, 32); a0y += __shfl_xor(a0y, 32);
    a1x += __shfl_xor(a1x, 32); a1y += __shfl_xor(a1y, 32);
    a2x += __shfl_xor(a2x, 32); a2y += __shfl_xor(a2y, 32);
    a3x += __shfl_xor(a3x, 32); a3y += __shfl_xor(a3y, 32);

    // half 0 writes bases 0,1; half 1 writes bases 2,3 (packed u32 = 2 bf16)
    float sLx = half ? a2x : a0x, sLy = half ? a2y : a0y;
    float sHx = half ? a3x : a1x, sHy = half ? a3y : a1y;
    unsigned* y32 = reinterpret_cast<unsigned*>(y + (size_t)n * 256);
    unsigned pL = (unsigned)f2bf(sLx) | ((unsigned)f2bf(sLy) << 16);
    unsigned pH = (unsigned)f2bf(sHx) | ((unsigned)f2bf(sHy) << 16);
    y32[(half * 2) * 32 + fl] = pL;
    y32[(half * 2 + 1) * 32 + fl] = pH;
}

// ---------------------------------------------------------------------------
// MFMA GEMM combine. A chunks: x (hi/lo split, full precision) + 4 y chunks
// (bf16 hi only). B (root/basis/W1) always hi/lo split. LDS rows padded to 72.

// stage A from f32 source, splitting into hi/lo bf16
__device__ __forceinline__ void stage_a_f32(const float* __restrict__ src, int blockM, int tid,
                                            unsigned short* Ah, unsigned short* Al) {
#pragma unroll
    for (int j = 0; j < 4; ++j) {
        int e4 = j * 256 + tid;
        int r = e4 >> 4;
        int c4 = (e4 & 15) << 2;
        int gr = blockM + r;
        if (gr > NN - 1) gr = NN - 1;
        float4 v = *reinterpret_cast<const float4*>(src + (size_t)gr * 64 + c4);
        ushort4v hv, lv;
        hv.x = f2bf(v.x); hv.y = f2bf(v.y); hv.z = f2bf(v.z); hv.w = f2bf(v.w);
        lv.x = f2bf(v.x - bf2f(hv.x));
        lv.y = f2bf(v.y - bf2f(hv.y));
        lv.z = f2bf(v.z - bf2f(hv.z));
        lv.w = f2bf(v.w - bf2f(hv.w));
        *reinterpret_cast<ushort4v*>(&Ah[r * 72 + c4]) = hv;
        *reinterpret_cast<ushort4v*>(&Al[r * 72 + c4]) = lv;
    }
}

// stage A from a bf16 plane (straight copy)
__device__ __forceinline__ void stage_a_bf(const unsigned short* __restrict__ src,
                                           long rowstride, int blockM, int tid,
                                           unsigned short* A) {
#pragma unroll
    for (int j = 0; j < 4; ++j) {
        int e4 = j * 256 + tid;
        int r = e4 >> 4;
        int c4 = (e4 & 15) << 2;
        int gr = blockM + r;
        if (gr > NN - 1) gr = NN - 1;
        ushort4v v = *reinterpret_cast<const ushort4v*>(src + (size_t)gr * rowstride + c4);
        *reinterpret_cast<ushort4v*>(&A[r * 72 + c4]) = v;
    }
}

// stage B tile transposed: src is [64 k][64 n] row-major -> LDS Bt[n][k], hi/lo
__device__ __forceinline__ void stage_b(const float* __restrict__ src, int tid,
                                        unsigned short* Bh, unsigned short* Bl) {
#pragma unroll
    for (int j = 0; j < 4; ++j) {
        int e4 = j * 256 + tid;
        int r = e4 >> 4;           // k index
        int c4 = (e4 & 15) << 2;   // n base
        float4 v = *reinterpret_cast<const float4*>(src + r * 64 + c4);
        unsigned short h0 = f2bf(v.x), h1 = f2bf(v.y), h2 = f2bf(v.z), h3 = f2bf(v.w);
        Bh[(c4 + 0) * 72 + r] = h0;
        Bh[(c4 + 1) * 72 + r] = h1;
        Bh[(c4 + 2) * 72 + r] = h2;
        Bh[(c4 + 3) * 72 + r] = h3;
        Bl[(c4 + 0) * 72 + r] = f2bf(v.x - bf2f(h0));
        Bl[(c4 + 1) * 72 + r] = f2bf(v.y - bf2f(h1));
        Bl[(c4 + 2) * 72 + r] = f2bf(v.z - bf2f(h2));
        Bl[(c4 + 3) * 72 + r] = f2bf(v.w - bf2f(h3));
    }
}

// K=64 chunk, full bf16x3 (A hi/lo): 6 MFMAs per n-tile
#define MFMA_CHUNK(ACC)                                                          \
    {                                                                            \
        short8 ah0 = *reinterpret_cast<const short8*>(&Ah[arow * 72 + kb]);      \
        short8 ah1 = *reinterpret_cast<const short8*>(&Ah[arow * 72 + 32 + kb]); \
        short8 al0 = *reinterpret_cast<const short8*>(&Al[arow * 72 + kb]);      \
        short8 al1 = *reinterpret_cast<const short8*>(&Al[arow * 72 + 32 + kb]); \
        _Pragma("unroll")                                                        \
        for (int t = 0; t < 4; ++t) {                                            \
            int bc = t * 16 + ln15;                                              \
            short8 bh0 = *reinterpret_cast<const short8*>(&Bh[bc * 72 + kb]);    \
            short8 bh1 = *reinterpret_cast<const short8*>(&Bh[bc * 72 + 32 + kb]);\
            short8 bl0 = *reinterpret_cast<const short8*>(&Bl[bc * 72 + kb]);    \
            short8 bl1 = *reinterpret_cast<const short8*>(&Bl[bc * 72 + 32 + kb]);\
            ACC[t] = __builtin_amdgcn_mfma_f32_16x16x32_bf16(ah0, bh0, ACC[t], 0, 0, 0); \
            ACC[t] = __builtin_amdgcn_mfma_f32_16x16x32_bf16(ah1, bh1, ACC[t], 0, 0, 0); \
            ACC[t] = __builtin_amdgcn_mfma_f32_16x16x32_bf16(ah0, bl0, ACC[t], 0, 0, 0); \
            ACC[t] = __builtin_amdgcn_mfma_f32_16x16x32_bf16(ah1, bl1, ACC[t], 0, 0, 0); \
            ACC[t] = __builtin_amdgcn_mfma_f32_16x16x32_bf16(al0, bh0, ACC[t], 0, 0, 0); \
            ACC[t] = __builtin_amdgcn_mfma_f32_16x16x32_bf16(al1, bh1, ACC[t], 0, 0, 0); \
        }                                                                        \
    }

// K=64 chunk, A hi only (bf16 source): 4 MFMAs per n-tile
#define MFMA_CHUNK_HI(ACC)                                                       \
    {                                                                            \
        short8 ah0 = *reinterpret_cast<const short8*>(&Ah[arow * 72 + kb]);      \
        short8 ah1 = *reinterpret_cast<const short8*>(&Ah[arow * 72 + 32 + kb]); \
        _Pragma("unroll")                                                        \
        for (int t = 0; t < 4; ++t) {                                            \
            int bc = t * 16 + ln15;                                              \
            short8 bh0 = *reinterpret_cast<const short8*>(&Bh[bc * 72 + kb]);    \
            short8 bh1 = *reinterpret_cast<const short8*>(&Bh[bc * 72 + 32 + kb]);\
            short8 bl0 = *reinterpret_cast<const short8*>(&Bl[bc * 72 + kb]);    \
            short8 bl1 = *reinterpret_cast<const short8*>(&Bl[bc * 72 + 32 + kb]);\
            ACC[t] = __builtin_amdgcn_mfma_f32_16x16x32_bf16(ah0, bh0, ACC[t], 0, 0, 0); \
            ACC[t] = __builtin_amdgcn_mfma_f32_16x16x32_bf16(ah1, bh1, ACC[t], 0, 0, 0); \
            ACC[t] = __builtin_amdgcn_mfma_f32_16x16x32_bf16(ah0, bl0, ACC[t], 0, 0, 0); \
            ACC[t] = __builtin_amdgcn_mfma_f32_16x16x32_bf16(ah1, bl1, ACC[t], 0, 0, 0); \
        }                                                                        \
    }

// XSPLIT=0: x chunk from f32 xin. XSPLIT=1: x chunk from bf16 planes xh/xl.
// PROJ=0: writes out as bf16 hi/lo planes (o1=hi, o2=lo), optional ReLU.
// PROJ=1: z -> W1 halves, writes o1=ha, o2=hb (bf16).
template <int RELU, int PROJ, int XSPLIT>
__global__ __launch_bounds__(256) void combine_mfma(
    const float* __restrict__ xin, const unsigned short* __restrict__ xh,
    const unsigned short* __restrict__ xl, const unsigned short* __restrict__ y,
    const float* __restrict__ basis, const float* __restrict__ root,
    const float* __restrict__ bias, const float* __restrict__ W1,
    unsigned short* __restrict__ o1, unsigned short* __restrict__ o2) {
    __shared__ unsigned short Ah[64 * 72], Al[64 * 72], Bh[64 * 72], Bl[64 * 72];
    int tid = threadIdx.x;
    int lane = tid & 63;
    int wid = tid >> 6;
    int ln15 = lane & 15;
    int blockM = blockIdx.x * 64;
    int wr = wid * 16;
    int arow = wr + ln15;
    int kb = (lane >> 4) * 8;

    f32x4 acc[4];
#pragma unroll
    for (int t = 0; t < 4; ++t) {
        float bv = bias[t * 16 + ln15];
        acc[t] = (f32x4){bv, bv, bv, bv};
    }

    // chunk 0: x @ root (full precision A)
    if (XSPLIT) {
        stage_a_bf(xh, 64, blockM, tid, Ah);
        stage_a_bf(xl, 64, blockM, tid, Al);
    } else {
        stage_a_f32(xin, blockM, tid, Ah, Al);
    }
    stage_b(root, tid, Bh, Bl);
    __syncthreads();
    MFMA_CHUNK(acc)

    // chunks 1..4: y_b @ basis_b (A = bf16 hi only)
    for (int c = 0; c < 4; ++c) {
        __syncthreads();
        stage_a_bf(y + c * 64, 256, blockM, tid, Ah);
        stage_b(basis + (size_t)c * 4096, tid, Bh, Bl);
        __syncthreads();
        MFMA_CHUNK_HI(acc)
    }

    if (!PROJ) {
        // D mapping (m89): col = lane&15, row = (lane>>4)*4 + i
#pragma unroll
        for (int t = 0; t < 4; ++t) {
            int cc = t * 16 + ln15;
#pragma unroll
            for (int i = 0; i < 4; ++i) {
                int gr = blockM + wr + (lane >> 4) * 4 + i;
                if (gr < NN) {
                    float v = acc[t][i];
                    if (RELU) v = fmaxf(v, 0.f);
                    unsigned short h = f2bf(v);
                    o1[(size_t)gr * 64 + cc] = h;
                    o2[(size_t)gr * 64 + cc] = f2bf(v - bf2f(h));
                }
            }
        }
    } else {
        // z (split bf16) back into Ah/Al, then two GEMM passes vs W1
#pragma unroll
        for (int t = 0; t < 4; ++t) {
            int cc = t * 16 + ln15;
#pragma unroll
            for (int i = 0; i < 4; ++i) {
                int r = wr + (lane >> 4) * 4 + i;
                float v = acc[t][i];
                unsigned short h = f2bf(v);
                Ah[r * 72 + cc] = h;
                Al[r * 72 + cc] = f2bf(v - bf2f(h));
            }
        }
        __syncthreads();
        stage_b(W1, tid, Bh, Bl);  // ha half
        __syncthreads();
        f32x4 acc2[4];
#pragma unroll
        for (int t = 0; t < 4; ++t) acc2[t] = (f32x4){0.f, 0.f, 0.f, 0.f};
        MFMA_CHUNK(acc2)
#pragma unroll
        for (int t = 0; t < 4; ++t) {
            int cc = t * 16 + ln15;
#pragma unroll
            for (int i = 0; i < 4; ++i) {
                int gr = blockM + wr + (lane >> 4) * 4 + i;
                if (gr < NN) o1[(size_t)gr * 64 + cc] = f2bf(acc2[t][i]);
            }
        }
        __syncthreads();
        stage_b(W1 + 64 * 64, tid, Bh, Bl);  // hb half
        __syncthreads();
#pragma unroll
        for (int t = 0; t < 4; ++t) acc2[t] = (f32x4){0.f, 0.f, 0.f, 0.f};
        MFMA_CHUNK(acc2)
#pragma unroll
        for (int t = 0; t < 4; ++t) {
            int cc = t * 16 + ln15;
#pragma unroll
            for (int i = 0; i < 4; ++i) {
                int gr = blockM + wr + (lane >> 4) * 4 + i;
                if (gr < NN) o2[(size_t)gr * 64 + cc] = f2bf(acc2[t][i]);
            }
        }
    }
}

// ---------------------------------------------------------------------------
// decode: 8 pairs per wave. lane = (pg = lane>>3, fg = lane&7);
// lane loads uint4 (8 bf16) of ha[a] and hb[b] at features fg*8..fg*8+7,
// per-lane partial dot, 3-step shfl reduce over the 8 fg lanes.
__global__ void decode_kernel(const int* __restrict__ pairs,
                              const unsigned short* __restrict__ ha,
                              const unsigned short* __restrict__ hb,
                              const float* __restrict__ b1, const float* __restrict__ W2,
                              const float* __restrict__ b2, float* __restrict__ out) {
    int lane = threadIdx.x & 63;
    int wid = threadIdx.x >> 6;
    int wpair0 = (blockIdx.x * 4 + wid) * 8;  // first pair of this wave
    int pg = lane >> 3;
    int fg = lane & 7;

    // 16 pair ints loaded by lanes 0..15, broadcast via shfl
    int pv = 0;
    if (lane < 16) pv = pairs[(size_t)wpair0 * 2 + lane];
    int a = __shfl(pv, pg * 2);
    int b = __shfl(pv, pg * 2 + 1);

    // fg-uniform parameter slices (L1-resident)
    const float4* b1p = reinterpret_cast<const float4*>(b1 + fg * 8);
    float4 b1a = b1p[0], b1b = b1p[1];
    const float4* w2p = reinterpret_cast<const float4*>(W2 + fg * 8);
    float4 w2a = w2p[0], w2b = w2p[1];

    uint4 hau = *reinterpret_cast<const uint4*>(ha + (size_t)a * 64 + fg * 8);
    uint4 hbu = *reinterpret_cast<const uint4*>(hb + (size_t)b * 64 + fg * 8);

    float s = 0.f;
    s += fmaxf(bf2f((unsigned short)(hau.x & 0xFFFF)) + bf2f((unsigned short)(hbu.x & 0xFFFF)) + b1a.x, 0.f) * w2a.x;
    s += fmaxf(bf2f((unsigned short)(hau.x >> 16))    + bf2f((unsigned short)(hbu.x >> 16))    + b1a.y, 0.f) * w2a.y;
    s += fmaxf(bf2f((unsigned short)(hau.y & 0xFFFF)) + bf2f((unsigned short)(hbu.y & 0xFFFF)) + b1a.z, 0.f) * w2a.z;
    s += fmaxf(bf2f((unsigned short)(hau.y >> 16))    + bf2f((unsigned short)(hbu.y >> 16))    + b1a.w, 0.f) * w2a.w;
    s += fmaxf(bf2f((unsigned short)(hau.z & 0xFFFF)) + bf2f((unsigned short)(hbu.z & 0xFFFF)) + b1b.x, 0.f) * w2b.x;
    s += fmaxf(bf2f((unsigned short)(hau.z >> 16))    + bf2f((unsigned short)(hbu.z >> 16))    + b1b.y, 0.f) * w2b.y;
    s += fmaxf(bf2f((unsigned short)(hau.w & 0xFFFF)) + bf2f((unsigned short)(hbu.w & 0xFFFF)) + b1b.z, 0.f) * w2b.z;
    s += fmaxf(bf2f((unsigned short)(hau.w >> 16))    + bf2f((unsigned short)(hbu.w >> 16))    + b1b.w, 0.f) * w2b.w;

    s += __shfl_xor(s, 1);
    s += __shfl_xor(s, 2);
    s += __shfl_xor(s, 4);
    if (fg == 0) out[wpair0 + pg] = s + b2[0];
}

// ---------------------------------------------------------------------------
static inline char* align64(char* p) {
    return (char*)(((uintptr_t)p + 63) & ~(uintptr_t)63);
}

extern "C" void kernel_launch(void* const* d_in, const int* in_sizes, int n_in,
                              void* d_out, int out_size, void* d_ws, size_t ws_size,
                              hipStream_t stream) {
    const int* edge_index = (const int*)d_in[0];
    const int* edge_type  = (const int*)d_in[1];
    const int* edge_pairs = (const int*)d_in[2];
    const float* node_emb = (const float*)d_in[3];
    const float* comp1 = (const float*)d_in[4];
    const float* basis1 = (const float*)d_in[5];
    const float* root1 = (const float*)d_in[6];
    const float* bias1 = (const float*)d_in[7];
    const float* comp2 = (const float*)d_in[8];
    const float* basis2 = (const float*)d_in[9];
    const float* root2 = (const float*)d_in[10];
    const float* bias2 = (const float*)d_in[11];
    const float* W1 = (const float*)d_in[12];
    const float* b1 = (const float*)d_in[13];
    const float* W2 = (const float*)d_in[14];
    const float* b2 = (const float*)d_in[15];

    const int* src = edge_index;
    const int* dst = edge_index + EE;

    // workspace layout (all regions 64B-aligned)
    char* w = (char*)d_ws;
    int* cnt        = (int*)w;            w = align64(w + sizeof(int) * NN);       // 400 KB
    int* bin_cursor = (int*)w;            w = align64(w + sizeof(int) * NBINS);    // (adjacent to cnt)
    uint2* ebin     = (uint2*)w;          w = align64(w + sizeof(uint2) * (size_t)NBINS * BINCAP);  // 16.8 MB
    unsigned* epack = (unsigned*)w;       w = align64(w + sizeof(unsigned) * (size_t)NN * CAP);     // 25.6 MB
    unsigned short* xemb = (unsigned short*)w; w = align64(w + sizeof(short) * (size_t)NN * 64);
    unsigned short* y    = (unsigned short*)w; w = align64(w + sizeof(short) * (size_t)NN * 256);
    unsigned short* x1h  = (unsigned short*)w; w = align64(w + sizeof(short) * (size_t)NN * 64);
    unsigned short* x1l  = (unsigned short*)w; w = align64(w + sizeof(short) * (size_t)NN * 64);
    unsigned short* hab  = (unsigned short*)w; w = align64(w + sizeof(short) * (size_t)NN * 64);
    unsigned short* hbb  = (unsigned short*)w; w = align64(w + sizeof(short) * (size_t)NN * 64);

    // ---- two-phase L2-confined CSR build ----
    hipMemsetAsync(cnt, 0, sizeof(int) * NN + 64, stream);  // cnt + bin_cursor (adjacent)
    bin_kernel<<<(EE + EPB - 1) / EPB, 256, 0, stream>>>(src, dst, edge_type, bin_cursor, ebin);
    scatter2_kernel<<<NBINS * 128, 256, 0, stream>>>(ebin, bin_cursor, cnt, epack);
    tobf16_kernel<<<(NN * 16 + 255) / 256, 256, 0, stream>>>(node_emb, xemb, NN * 16);

    // ---- layer 1: node_emb -> x1 (hi/lo bf16 planes, relu) ----
    aggregate_kernel<<<NN / 4, 256, 0, stream>>>(xemb, epack, cnt, comp1, y);
    combine_mfma<1, 0, 0><<<(NN + 63) / 64, 256, 0, stream>>>(
        node_emb, nullptr, nullptr, y, basis1, root1, bias1, nullptr, x1h, x1l);

    // ---- layer 2 (+decoder projection fused): x1 -> ha/hb (bf16) ----
    aggregate_kernel<<<NN / 4, 256, 0, stream>>>(x1h, epack, cnt, comp2, y);
    combine_mfma<0, 1, 1><<<(NN + 63) / 64, 256, 0, stream>>>(
        nullptr, x1h, x1l, y, basis2, root2, bias2, W1, hab, hbb);

    // ---- decoder ----
    decode_kernel<<<PP / 32, 256, 0, stream>>>(edge_pairs, hab, hbb, b1, W2, b2, (float*)d_out);
}

// Round 11
// 335.895 us; speedup vs baseline: 1.1876x; 1.1876x over previous
//
#include <hip/hip_runtime.h>

// Problem constants (fixed by the reference setup)
constexpr int NN = 100000;   // nodes
constexpr int RR = 8;        // relations
constexpr int BB = 4;        // bases
constexpr int DD = 64;       // feature dim
constexpr int EE = 2000000;  // edges
constexpr int PP = 500000;   // pairs
constexpr int CAP = 64;      // fixed per-node bucket capacity (deg ~ Poisson(20))

constexpr int NBIN = 196;      // ceil(100000 / 512) node-range bins
constexpr int BINCAP = 16384;  // per-bin record cap (expect ~10.2k, >60 sigma slack)
constexpr int EPB = 4096;      // edges per bin_kernel block (16/thread)

typedef __attribute__((ext_vector_type(8))) short short8;      // 8 bf16 MFMA frag
typedef __attribute__((ext_vector_type(4))) unsigned short ushort4v;
typedef __attribute__((ext_vector_type(4))) float f32x4;

// ---------------------------------------------------------------------------
// bf16 helpers (RNE)
__device__ __forceinline__ unsigned short f2bf(float f) {
    unsigned u = __float_as_uint(f);
    u += 0x7FFFu + ((u >> 16) & 1u);
    return (unsigned short)(u >> 16);
}
__device__ __forceinline__ float bf2f(unsigned short b) {
    return __uint_as_float(((unsigned)b) << 16);
}

// f32 -> bf16 plane copy (vectorized)
__global__ void tobf16_kernel(const float* __restrict__ in, unsigned short* __restrict__ out,
                              int n4) {
    int i = blockIdx.x * blockDim.x + threadIdx.x;
    if (i >= n4) return;
    float4 v = reinterpret_cast<const float4*>(in)[i];
    ushort4v o;
    o.x = f2bf(v.x); o.y = f2bf(v.y); o.z = f2bf(v.z); o.w = f2bf(v.w);
    reinterpret_cast<ushort4v*>(out)[i] = o;
}

// ---------------------------------------------------------------------------
// Phase 1: partition edges into 196 bins by dst>>9. Record = src | et<<17 |
// dstlocal<<20 (29 bits, 4 B). LDS histogram -> one global atomic per bin.
__global__ void bin_kernel(const int* __restrict__ src, const int* __restrict__ dst,
                           const int* __restrict__ et, int* __restrict__ bin_cursor,
                           unsigned* __restrict__ ebin) {
    __shared__ int lcount[NBIN];
    __shared__ int lbase[NBIN];
    int tid = threadIdx.x;
    for (int i = tid; i < NBIN; i += 256) lcount[i] = 0;
    __syncthreads();

    int e0 = blockIdx.x * EPB;
    unsigned rec[16];
    int rnk[16];
    int bn[16];
#pragma unroll
    for (int j = 0; j < 16; ++j) {
        int e = e0 + j * 256 + tid;
        if (e < EE) {
            int d = dst[e];
            int b = d >> 9;
            bn[j] = b;
            rec[j] = (unsigned)src[e] | ((unsigned)et[e] << 17) | ((unsigned)(d & 511) << 20);
            rnk[j] = atomicAdd(&lcount[b], 1);
        } else {
            rnk[j] = -1;
        }
    }
    __syncthreads();
    for (int i = tid; i < NBIN; i += 256) lbase[i] = atomicAdd(&bin_cursor[i], lcount[i]);
    __syncthreads();
#pragma unroll
    for (int j = 0; j < 16; ++j) {
        if (rnk[j] >= 0) {
            int pos = lbase[bn[j]] + rnk[j];
            if (pos < BINCAP) ebin[(size_t)bn[j] * BINCAP + pos] = rec[j];
        }
    }
}

// Phase 2: ONE block per bin. Ranks via LDS atomics (no device-scope atomic
// per edge); the block's 128 KB epack region stays L2-resident and is written
// back once. cnt written coalesced from LDS at the end (no cnt memset needed).
__global__ __launch_bounds__(1024) void bucket_kernel(
    const unsigned* __restrict__ ebin, const int* __restrict__ bin_cursor,
    int* __restrict__ cnt, unsigned* __restrict__ epack) {
    __shared__ int lcnt[512];
    int bin = blockIdx.x;
    int tid = threadIdx.x;
    for (int i = tid; i < 512; i += 1024) lcnt[i] = 0;
    __syncthreads();

    int m = bin_cursor[bin];
    if (m > BINCAP) m = BINCAP;
    const unsigned* base = ebin + (size_t)bin * BINCAP;
    int nodebase = bin << 9;

    for (int i = tid; i < m; i += 1024) {
        unsigned rec = base[i];
        int dl = rec >> 20;
        int r = atomicAdd(&lcnt[dl], 1);
        if (r < CAP)
            epack[(size_t)(nodebase + dl) * CAP + r] = rec & 0xFFFFFu;  // src | et<<17
    }
    __syncthreads();
    for (int i = tid; i < 512; i += 1024) {
        int n = nodebase + i;
        if (n < NN) cnt[n] = lcnt[i];
    }
}

// ---------------------------------------------------------------------------
// Basis-space aggregation over bf16 features, fixed-bucket CSR (deg <= 64 ->
// exactly one 64-edge window). Payload: src = p & 0x1FFFF, et = p >> 17.
// Per-relation mean denominators via ballot/popcount. Half-wave h (lane>>5)
// processes edges k+h; lane covers features 2*(lane&31)+{0,1}.
__global__ void aggregate_kernel(const unsigned short* __restrict__ x,
                                 const unsigned* __restrict__ epack,
                                 const int* __restrict__ cnt,
                                 const float* __restrict__ comp,
                                 unsigned short* __restrict__ y) {
    __shared__ float wlds[4 * 32];  // [wave][r*4+b]
    int lane = threadIdx.x & 63;
    int wid = threadIdx.x >> 6;
    int n = blockIdx.x * 4 + wid;
    int half = lane >> 5;
    int fl = lane & 31;

    int m = cnt[n];
    if (m > CAP) m = CAP;

    unsigned pl = (lane < m) ? epack[(size_t)n * CAP + lane] : 0u;
    int et_l = (int)(pl >> 17);

    // per-relation counts via 8 wave-wide ballots (register-only, uniform)
    int cr0 = __popcll(__ballot((lane < m) && (et_l == 0)));
    int cr1 = __popcll(__ballot((lane < m) && (et_l == 1)));
    int cr2 = __popcll(__ballot((lane < m) && (et_l == 2)));
    int cr3 = __popcll(__ballot((lane < m) && (et_l == 3)));
    int cr4 = __popcll(__ballot((lane < m) && (et_l == 4)));
    int cr5 = __popcll(__ballot((lane < m) && (et_l == 5)));
    int cr6 = __popcll(__ballot((lane < m) && (et_l == 6)));
    int cr7 = __popcll(__ballot((lane < m) && (et_l == 7)));

    if (lane < 32) {
        int r = lane >> 2;
        int myc = cr0;
        myc = (r == 1) ? cr1 : myc;
        myc = (r == 2) ? cr2 : myc;
        myc = (r == 3) ? cr3 : myc;
        myc = (r == 4) ? cr4 : myc;
        myc = (r == 5) ? cr5 : myc;
        myc = (r == 6) ? cr6 : myc;
        myc = (r == 7) ? cr7 : myc;
        wlds[wid * 32 + lane] = comp[lane] / fmaxf((float)myc, 1.f);
    }
    __syncthreads();

    float a0x = 0.f, a0y = 0.f, a1x = 0.f, a1y = 0.f;
    float a2x = 0.f, a2y = 0.f, a3x = 0.f, a3y = 0.f;

    int k = 0;
    for (; k + 4 <= m; k += 4) {  // 4 edges per iteration (2 per half-wave)
        unsigned pA = __shfl(pl, k + half);
        unsigned pB = __shfl(pl, k + 2 + half);
        unsigned rA = *reinterpret_cast<const unsigned*>(
            x + (size_t)(pA & 0x1FFFFu) * 64 + fl * 2);
        unsigned rB = *reinterpret_cast<const unsigned*>(
            x + (size_t)(pB & 0x1FFFFu) * 64 + fl * 2);
        float4 wA = *reinterpret_cast<const float4*>(&wlds[wid * 32 + (pA >> 17) * 4]);
        float4 wB = *reinterpret_cast<const float4*>(&wlds[wid * 32 + (pB >> 17) * 4]);
        float rAx = bf2f((unsigned short)(rA & 0xFFFF));
        float rAy = bf2f((unsigned short)(rA >> 16));
        float rBx = bf2f((unsigned short)(rB & 0xFFFF));
        float rBy = bf2f((unsigned short)(rB >> 16));
        a0x = fmaf(wA.x, rAx, a0x); a0y = fmaf(wA.x, rAy, a0y);
        a1x = fmaf(wA.y, rAx, a1x); a1y = fmaf(wA.y, rAy, a1y);
        a2x = fmaf(wA.z, rAx, a2x); a2y = fmaf(wA.z, rAy, a2y);
        a3x = fmaf(wA.w, rAx, a3x); a3y = fmaf(wA.w, rAy, a3y);
        a0x = fmaf(wB.x, rBx, a0x); a0y = fmaf(wB.x, rBy, a0y);
        a1x = fmaf(wB.y, rBx, a1x); a1y = fmaf(wB.y, rBy, a1y);
        a2x = fmaf(wB.z, rBx, a2x); a2y = fmaf(wB.z, rBy, a2y);
        a3x = fmaf(wB.w, rBx, a3x); a3y = fmaf(wB.w, rBy, a3y);
    }
    for (; k < m; k += 2) {  // 0..3 remaining edges
        int ki = k + half;
        int kc = (ki < m) ? ki : k;
        float sc = (ki < m) ? 1.f : 0.f;
        unsigned p = __shfl(pl, kc);
        unsigned rv = *reinterpret_cast<const unsigned*>(
            x + (size_t)(p & 0x1FFFFu) * 64 + fl * 2);
        float4 wv = *reinterpret_cast<const float4*>(&wlds[wid * 32 + (p >> 17) * 4]);
        float rx = bf2f((unsigned short)(rv & 0xFFFF)) * sc;
        float ry = bf2f((unsigned short)(rv >> 16)) * sc;
        a0x = fmaf(wv.x, rx, a0x); a0y = fmaf(wv.x, ry, a0y);
        a1x = fmaf(wv.y, rx, a1x); a1y = fmaf(wv.y, ry, a1y);
        a2x = fmaf(wv.z, rx, a2x); a2y = fmaf(wv.z, ry, a2y);
        a3x = fmaf(wv.w, rx, a3x); a3y = fmaf(wv.w, ry, a3y);
    }

    // merge the two half-wave partial sums
    a0x += __shfl_xor(a0x, 32); a0y += __shfl_xor(a0y, 32);
    a1x += __shfl_xor(a1x, 32); a1y += __shfl_xor(a1y, 32);
    a2x += __shfl_xor(a2x, 32); a2y += __shfl_xor(a2y, 32);
    a3x += __shfl_xor(a3x, 32); a3y += __shfl_xor(a3y, 32);

    // half 0 writes bases 0,1; half 1 writes bases 2,3 (packed u32 = 2 bf16)
    float sLx = half ? a2x : a0x, sLy = half ? a2y : a0y;
    float sHx = half ? a3x : a1x, sHy = half ? a3y : a1y;
    unsigned* y32 = reinterpret_cast<unsigned*>(y + (size_t)n * 256);
    unsigned pL = (unsigned)f2bf(sLx) | ((unsigned)f2bf(sLy) << 16);
    unsigned pH = (unsigned)f2bf(sHx) | ((unsigned)f2bf(sHy) << 16);
    y32[(half * 2) * 32 + fl] = pL;
    y32[(half * 2 + 1) * 32 + fl] = pH;
}

// ---------------------------------------------------------------------------
// MFMA GEMM combine. A chunks: x (hi/lo split, full precision) + 4 y chunks
// (bf16 hi only). B (root/basis/W1) always hi/lo split. LDS rows padded to 72.

// stage A from f32 source, splitting into hi/lo bf16
__device__ __forceinline__ void stage_a_f32(const float* __restrict__ src, int blockM, int tid,
                                            unsigned short* Ah, unsigned short* Al) {
#pragma unroll
    for (int j = 0; j < 4; ++j) {
        int e4 = j * 256 + tid;
        int r = e4 >> 4;
        int c4 = (e4 & 15) << 2;
        int gr = blockM + r;
        if (gr > NN - 1) gr = NN - 1;
        float4 v = *reinterpret_cast<const float4*>(src + (size_t)gr * 64 + c4);
        ushort4v hv, lv;
        hv.x = f2bf(v.x); hv.y = f2bf(v.y); hv.z = f2bf(v.z); hv.w = f2bf(v.w);
        lv.x = f2bf(v.x - bf2f(hv.x));
        lv.y = f2bf(v.y - bf2f(hv.y));
        lv.z = f2bf(v.z - bf2f(hv.z));
        lv.w = f2bf(v.w - bf2f(hv.w));
        *reinterpret_cast<ushort4v*>(&Ah[r * 72 + c4]) = hv;
        *reinterpret_cast<ushort4v*>(&Al[r * 72 + c4]) = lv;
    }
}

// stage A from a bf16 plane (straight copy)
__device__ __forceinline__ void stage_a_bf(const unsigned short* __restrict__ src,
                                           long rowstride, int blockM, int tid,
                                           unsigned short* A) {
#pragma unroll
    for (int j = 0; j < 4; ++j) {
        int e4 = j * 256 + tid;
        int r = e4 >> 4;
        int c4 = (e4 & 15) << 2;
        int gr = blockM + r;
        if (gr > NN - 1) gr = NN - 1;
        ushort4v v = *reinterpret_cast<const ushort4v*>(src + (size_t)gr * rowstride + c4);
        *reinterpret_cast<ushort4v*>(&A[r * 72 + c4]) = v;
    }
}

// stage B tile transposed: src is [64 k][64 n] row-major -> LDS Bt[n][k], hi/lo
__device__ __forceinline__ void stage_b(const float* __restrict__ src, int tid,
                                        unsigned short* Bh, unsigned short* Bl) {
#pragma unroll
    for (int j = 0; j < 4; ++j) {
        int e4 = j * 256 + tid;
        int r = e4 >> 4;           // k index
        int c4 = (e4 & 15) << 2;   // n base
        float4 v = *reinterpret_cast<const float4*>(src + r * 64 + c4);
        unsigned short h0 = f2bf(v.x), h1 = f2bf(v.y), h2 = f2bf(v.z), h3 = f2bf(v.w);
        Bh[(c4 + 0) * 72 + r] = h0;
        Bh[(c4 + 1) * 72 + r] = h1;
        Bh[(c4 + 2) * 72 + r] = h2;
        Bh[(c4 + 3) * 72 + r] = h3;
        Bl[(c4 + 0) * 72 + r] = f2bf(v.x - bf2f(h0));
        Bl[(c4 + 1) * 72 + r] = f2bf(v.y - bf2f(h1));
        Bl[(c4 + 2) * 72 + r] = f2bf(v.z - bf2f(h2));
        Bl[(c4 + 3) * 72 + r] = f2bf(v.w - bf2f(h3));
    }
}

// K=64 chunk, full bf16x3 (A hi/lo): 6 MFMAs per n-tile
#define MFMA_CHUNK(ACC)                                                          \
    {                                                                            \
        short8 ah0 = *reinterpret_cast<const short8*>(&Ah[arow * 72 + kb]);      \
        short8 ah1 = *reinterpret_cast<const short8*>(&Ah[arow * 72 + 32 + kb]); \
        short8 al0 = *reinterpret_cast<const short8*>(&Al[arow * 72 + kb]);      \
        short8 al1 = *reinterpret_cast<const short8*>(&Al[arow * 72 + 32 + kb]); \
        _Pragma("unroll")                                                        \
        for (int t = 0; t < 4; ++t) {                                            \
            int bc = t * 16 + ln15;                                              \
            short8 bh0 = *reinterpret_cast<const short8*>(&Bh[bc * 72 + kb]);    \
            short8 bh1 = *reinterpret_cast<const short8*>(&Bh[bc * 72 + 32 + kb]);\
            short8 bl0 = *reinterpret_cast<const short8*>(&Bl[bc * 72 + kb]);    \
            short8 bl1 = *reinterpret_cast<const short8*>(&Bl[bc * 72 + 32 + kb]);\
            ACC[t] = __builtin_amdgcn_mfma_f32_16x16x32_bf16(ah0, bh0, ACC[t], 0, 0, 0); \
            ACC[t] = __builtin_amdgcn_mfma_f32_16x16x32_bf16(ah1, bh1, ACC[t], 0, 0, 0); \
            ACC[t] = __builtin_amdgcn_mfma_f32_16x16x32_bf16(ah0, bl0, ACC[t], 0, 0, 0); \
            ACC[t] = __builtin_amdgcn_mfma_f32_16x16x32_bf16(ah1, bl1, ACC[t], 0, 0, 0); \
            ACC[t] = __builtin_amdgcn_mfma_f32_16x16x32_bf16(al0, bh0, ACC[t], 0, 0, 0); \
            ACC[t] = __builtin_amdgcn_mfma_f32_16x16x32_bf16(al1, bh1, ACC[t], 0, 0, 0); \
        }                                                                        \
    }

// K=64 chunk, A hi only (bf16 source): 4 MFMAs per n-tile
#define MFMA_CHUNK_HI(ACC)                                                       \
    {                                                                            \
        short8 ah0 = *reinterpret_cast<const short8*>(&Ah[arow * 72 + kb]);      \
        short8 ah1 = *reinterpret_cast<const short8*>(&Ah[arow * 72 + 32 + kb]); \
        _Pragma("unroll")                                                        \
        for (int t = 0; t < 4; ++t) {                                            \
            int bc = t * 16 + ln15;                                              \
            short8 bh0 = *reinterpret_cast<const short8*>(&Bh[bc * 72 + kb]);    \
            short8 bh1 = *reinterpret_cast<const short8*>(&Bh[bc * 72 + 32 + kb]);\
            short8 bl0 = *reinterpret_cast<const short8*>(&Bl[bc * 72 + kb]);    \
            short8 bl1 = *reinterpret_cast<const short8*>(&Bl[bc * 72 + 32 + kb]);\
            ACC[t] = __builtin_amdgcn_mfma_f32_16x16x32_bf16(ah0, bh0, ACC[t], 0, 0, 0); \
            ACC[t] = __builtin_amdgcn_mfma_f32_16x16x32_bf16(ah1, bh1, ACC[t], 0, 0, 0); \
            ACC[t] = __builtin_amdgcn_mfma_f32_16x16x32_bf16(ah0, bl0, ACC[t], 0, 0, 0); \
            ACC[t] = __builtin_amdgcn_mfma_f32_16x16x32_bf16(ah1, bl1, ACC[t], 0, 0, 0); \
        }                                                                        \
    }

// XSPLIT=0: x chunk from f32 xin. XSPLIT=1: x chunk from bf16 planes xh/xl.
// PROJ=0: writes out as bf16 hi/lo planes (o1=hi, o2=lo), optional ReLU.
// PROJ=1: z -> W1 halves, writes o1=ha, o2=hb (bf16).
template <int RELU, int PROJ, int XSPLIT>
__global__ __launch_bounds__(256) void combine_mfma(
    const float* __restrict__ xin, const unsigned short* __restrict__ xh,
    const unsigned short* __restrict__ xl, const unsigned short* __restrict__ y,
    const float* __restrict__ basis, const float* __restrict__ root,
    const float* __restrict__ bias, const float* __restrict__ W1,
    unsigned short* __restrict__ o1, unsigned short* __restrict__ o2) {
    __shared__ unsigned short Ah[64 * 72], Al[64 * 72], Bh[64 * 72], Bl[64 * 72];
    int tid = threadIdx.x;
    int lane = tid & 63;
    int wid = tid >> 6;
    int ln15 = lane & 15;
    int blockM = blockIdx.x * 64;
    int wr = wid * 16;
    int arow = wr + ln15;
    int kb = (lane >> 4) * 8;

    f32x4 acc[4];
#pragma unroll
    for (int t = 0; t < 4; ++t) {
        float bv = bias[t * 16 + ln15];
        acc[t] = (f32x4){bv, bv, bv, bv};
    }

    // chunk 0: x @ root (full precision A)
    if (XSPLIT) {
        stage_a_bf(xh, 64, blockM, tid, Ah);
        stage_a_bf(xl, 64, blockM, tid, Al);
    } else {
        stage_a_f32(xin, blockM, tid, Ah, Al);
    }
    stage_b(root, tid, Bh, Bl);
    __syncthreads();
    MFMA_CHUNK(acc)

    // chunks 1..4: y_b @ basis_b (A = bf16 hi only)
    for (int c = 0; c < 4; ++c) {
        __syncthreads();
        stage_a_bf(y + c * 64, 256, blockM, tid, Ah);
        stage_b(basis + (size_t)c * 4096, tid, Bh, Bl);
        __syncthreads();
        MFMA_CHUNK_HI(acc)
    }

    if (!PROJ) {
        // D mapping (m89): col = lane&15, row = (lane>>4)*4 + i
#pragma unroll
        for (int t = 0; t < 4; ++t) {
            int cc = t * 16 + ln15;
#pragma unroll
            for (int i = 0; i < 4; ++i) {
                int gr = blockM + wr + (lane >> 4) * 4 + i;
                if (gr < NN) {
                    float v = acc[t][i];
                    if (RELU) v = fmaxf(v, 0.f);
                    unsigned short h = f2bf(v);
                    o1[(size_t)gr * 64 + cc] = h;
                    o2[(size_t)gr * 64 + cc] = f2bf(v - bf2f(h));
                }
            }
        }
    } else {
        // z (split bf16) back into Ah/Al, then two GEMM passes vs W1
#pragma unroll
        for (int t = 0; t < 4; ++t) {
            int cc = t * 16 + ln15;
#pragma unroll
            for (int i = 0; i < 4; ++i) {
                int r = wr + (lane >> 4) * 4 + i;
                float v = acc[t][i];
                unsigned short h = f2bf(v);
                Ah[r * 72 + cc] = h;
                Al[r * 72 + cc] = f2bf(v - bf2f(h));
            }
        }
        __syncthreads();
        stage_b(W1, tid, Bh, Bl);  // ha half
        __syncthreads();
        f32x4 acc2[4];
#pragma unroll
        for (int t = 0; t < 4; ++t) acc2[t] = (f32x4){0.f, 0.f, 0.f, 0.f};
        MFMA_CHUNK(acc2)
#pragma unroll
        for (int t = 0; t < 4; ++t) {
            int cc = t * 16 + ln15;
#pragma unroll
            for (int i = 0; i < 4; ++i) {
                int gr = blockM + wr + (lane >> 4) * 4 + i;
                if (gr < NN) o1[(size_t)gr * 64 + cc] = f2bf(acc2[t][i]);
            }
        }
        __syncthreads();
        stage_b(W1 + 64 * 64, tid, Bh, Bl);  // hb half
        __syncthreads();
#pragma unroll
        for (int t = 0; t < 4; ++t) acc2[t] = (f32x4){0.f, 0.f, 0.f, 0.f};
        MFMA_CHUNK(acc2)
#pragma unroll
        for (int t = 0; t < 4; ++t) {
            int cc = t * 16 + ln15;
#pragma unroll
            for (int i = 0; i < 4; ++i) {
                int gr = blockM + wr + (lane >> 4) * 4 + i;
                if (gr < NN) o2[(size_t)gr * 64 + cc] = f2bf(acc2[t][i]);
            }
        }
    }
}

// ---------------------------------------------------------------------------
// decode: 8 pairs per wave. lane = (pg = lane>>3, fg = lane&7);
// lane loads uint4 (8 bf16) of ha[a] and hb[b] at features fg*8..fg*8+7,
// per-lane partial dot, 3-step shfl reduce over the 8 fg lanes.
__global__ void decode_kernel(const int* __restrict__ pairs,
                              const unsigned short* __restrict__ ha,
                              const unsigned short* __restrict__ hb,
                              const float* __restrict__ b1, const float* __restrict__ W2,
                              const float* __restrict__ b2, float* __restrict__ out) {
    int lane = threadIdx.x & 63;
    int wid = threadIdx.x >> 6;
    int wpair0 = (blockIdx.x * 4 + wid) * 8;  // first pair of this wave
    int pg = lane >> 3;
    int fg = lane & 7;

    // 16 pair ints loaded by lanes 0..15, broadcast via shfl
    int pv = 0;
    if (lane < 16) pv = pairs[(size_t)wpair0 * 2 + lane];
    int a = __shfl(pv, pg * 2);
    int b = __shfl(pv, pg * 2 + 1);

    // fg-uniform parameter slices (L1-resident)
    const float4* b1p = reinterpret_cast<const float4*>(b1 + fg * 8);
    float4 b1a = b1p[0], b1b = b1p[1];
    const float4* w2p = reinterpret_cast<const float4*>(W2 + fg * 8);
    float4 w2a = w2p[0], w2b = w2p[1];

    uint4 hau = *reinterpret_cast<const uint4*>(ha + (size_t)a * 64 + fg * 8);
    uint4 hbu = *reinterpret_cast<const uint4*>(hb + (size_t)b * 64 + fg * 8);

    float s = 0.f;
    s += fmaxf(bf2f((unsigned short)(hau.x & 0xFFFF)) + bf2f((unsigned short)(hbu.x & 0xFFFF)) + b1a.x, 0.f) * w2a.x;
    s += fmaxf(bf2f((unsigned short)(hau.x >> 16))    + bf2f((unsigned short)(hbu.x >> 16))    + b1a.y, 0.f) * w2a.y;
    s += fmaxf(bf2f((unsigned short)(hau.y & 0xFFFF)) + bf2f((unsigned short)(hbu.y & 0xFFFF)) + b1a.z, 0.f) * w2a.z;
    s += fmaxf(bf2f((unsigned short)(hau.y >> 16))    + bf2f((unsigned short)(hbu.y >> 16))    + b1a.w, 0.f) * w2a.w;
    s += fmaxf(bf2f((unsigned short)(hau.z & 0xFFFF)) + bf2f((unsigned short)(hbu.z & 0xFFFF)) + b1b.x, 0.f) * w2b.x;
    s += fmaxf(bf2f((unsigned short)(hau.z >> 16))    + bf2f((unsigned short)(hbu.z >> 16))    + b1b.y, 0.f) * w2b.y;
    s += fmaxf(bf2f((unsigned short)(hau.w & 0xFFFF)) + bf2f((unsigned short)(hbu.w & 0xFFFF)) + b1b.z, 0.f) * w2b.z;
    s += fmaxf(bf2f((unsigned short)(hau.w >> 16))    + bf2f((unsigned short)(hbu.w >> 16))    + b1b.w, 0.f) * w2b.w;

    s += __shfl_xor(s, 1);
    s += __shfl_xor(s, 2);
    s += __shfl_xor(s, 4);
    if (fg == 0) out[wpair0 + pg] = s + b2[0];
}

// ---------------------------------------------------------------------------
static inline char* align64(char* p) {
    return (char*)(((uintptr_t)p + 63) & ~(uintptr_t)63);
}

extern "C" void kernel_launch(void* const* d_in, const int* in_sizes, int n_in,
                              void* d_out, int out_size, void* d_ws, size_t ws_size,
                              hipStream_t stream) {
    const int* edge_index = (const int*)d_in[0];
    const int* edge_type  = (const int*)d_in[1];
    const int* edge_pairs = (const int*)d_in[2];
    const float* node_emb = (const float*)d_in[3];
    const float* comp1 = (const float*)d_in[4];
    const float* basis1 = (const float*)d_in[5];
    const float* root1 = (const float*)d_in[6];
    const float* bias1 = (const float*)d_in[7];
    const float* comp2 = (const float*)d_in[8];
    const float* basis2 = (const float*)d_in[9];
    const float* root2 = (const float*)d_in[10];
    const float* bias2 = (const float*)d_in[11];
    const float* W1 = (const float*)d_in[12];
    const float* b1 = (const float*)d_in[13];
    const float* W2 = (const float*)d_in[14];
    const float* b2 = (const float*)d_in[15];

    const int* src = edge_index;
    const int* dst = edge_index + EE;

    // workspace layout (all regions 64B-aligned)
    char* w = (char*)d_ws;
    int* bin_cursor = (int*)w;            w = align64(w + sizeof(int) * NBIN);     // 784 B
    int* cnt        = (int*)w;            w = align64(w + sizeof(int) * NN);       // 400 KB
    unsigned* ebin  = (unsigned*)w;       w = align64(w + sizeof(unsigned) * (size_t)NBIN * BINCAP);  // 12.8 MB
    unsigned* epack = (unsigned*)w;       w = align64(w + sizeof(unsigned) * (size_t)NN * CAP);       // 25.6 MB
    unsigned short* xemb = (unsigned short*)w; w = align64(w + sizeof(short) * (size_t)NN * 64);
    unsigned short* y    = (unsigned short*)w; w = align64(w + sizeof(short) * (size_t)NN * 256);
    unsigned short* x1h  = (unsigned short*)w; w = align64(w + sizeof(short) * (size_t)NN * 64);
    unsigned short* x1l  = (unsigned short*)w; w = align64(w + sizeof(short) * (size_t)NN * 64);
    unsigned short* hab  = (unsigned short*)w; w = align64(w + sizeof(short) * (size_t)NN * 64);
    unsigned short* hbb  = (unsigned short*)w; w = align64(w + sizeof(short) * (size_t)NN * 64);

    // ---- CSR build: bin by dst>>9, then one block per bin with LDS ranks ----
    hipMemsetAsync(bin_cursor, 0, sizeof(int) * NBIN, stream);
    bin_kernel<<<(EE + EPB - 1) / EPB, 256, 0, stream>>>(src, dst, edge_type, bin_cursor, ebin);
    bucket_kernel<<<NBIN, 1024, 0, stream>>>(ebin, bin_cursor, cnt, epack);
    tobf16_kernel<<<(NN * 16 + 255) / 256, 256, 0, stream>>>(node_emb, xemb, NN * 16);

    // ---- layer 1: node_emb -> x1 (hi/lo bf16 planes, relu) ----
    aggregate_kernel<<<NN / 4, 256, 0, stream>>>(xemb, epack, cnt, comp1, y);
    combine_mfma<1, 0, 0><<<(NN + 63) / 64, 256, 0, stream>>>(
        node_emb, nullptr, nullptr, y, basis1, root1, bias1, nullptr, x1h, x1l);

    // ---- layer 2 (+decoder projection fused): x1 -> ha/hb (bf16) ----
    aggregate_kernel<<<NN / 4, 256, 0, stream>>>(x1h, epack, cnt, comp2, y);
    combine_mfma<0, 1, 1><<<(NN + 63) / 64, 256, 0, stream>>>(
        nullptr, x1h, x1l, y, basis2, root2, bias2, W1, hab, hbb);

    // ---- decoder ----
    decode_kernel<<<PP / 32, 256, 0, stream>>>(edge_pairs, hab, hbb, b1, W2, b2, (float*)d_out);
}